// Round 5
// baseline (532.997 us; speedup 1.0000x reference)
//
#include <hip/hip_runtime.h>
#include <math.h>

// ---- problem constants ----
#define TT 2048
#define HH 1024
#define NHEADS 16
#define NKVH 4
#define HDIM 64
#define NEXP 32
#define TOPK_ 4
#define NGRP 4
#define IMID 384
#define ISHARED 384
#define QKV_W (24*64)   // 1536
#define EPS_ 1e-5f

typedef __attribute__((ext_vector_type(8))) short short8;
typedef __attribute__((ext_vector_type(4))) float f32x4;

__device__ __forceinline__ ushort f2bf(float x) {
  union { float f; unsigned u; } v; v.f = x;
  unsigned r = v.u + 0x7fffu + ((v.u >> 16) & 1u);
  return (ushort)(r >> 16);
}

// =====================================================================
// MFMA GEMM building blocks (verified round 1). Tile 64x64, BK=32.
// Fragment layouts (16x16x32 bf16):
//   A-frag lane l: A[row = l&15][k in {4g+j, 16+4g+j}], g = l>>4
//   B-frag lane l: B[k in {4g+j, 16+4g+j}][col = l&15]
//   => A-frag(X) is bitwise identical to B-frag(X^T).
//   C lane l: C[row=(l>>4)*4+i][col = l&15]
// =====================================================================
__device__ __forceinline__ void stage_A_tile(const float* __restrict__ arow,
                                             int k0, ushort* As, int tid) {
  int g = tid & 3, r = tid >> 2;
  const float* p = arow + k0 + 4 * g;
  float4 h0 = *(const float4*)p;
  float4 h1 = *(const float4*)(p + 16);
  short8 v;
  v[0] = (short)f2bf(h0.x); v[1] = (short)f2bf(h0.y);
  v[2] = (short)f2bf(h0.z); v[3] = (short)f2bf(h0.w);
  v[4] = (short)f2bf(h1.x); v[5] = (short)f2bf(h1.y);
  v[6] = (short)f2bf(h1.z); v[7] = (short)f2bf(h1.w);
  *(short8*)(As + ((g * 64 + (r ^ g)) * 8)) = v;
}

__device__ __forceinline__ void stage_B_tile(const float* __restrict__ B, int ldb,
                                             int k0, int col0, ushort* Bs, int tid) {
  int a = tid >> 4;            // k rows {2a, 2a+1}
  int cG = tid & 15;           // column quad
  int k = 2 * a;
  const float* p0 = B + (size_t)(k0 + k) * ldb + col0 + cG * 4;
  const float* p1 = p0 + ldb;
  float4 r0 = *(const float4*)p0;
  float4 r1 = *(const float4*)p1;
  int g = (k & 15) >> 2;
  int slot = (k & 3) + ((k >> 4) << 2);
  float v0[4] = {r0.x, r0.y, r0.z, r0.w};
  float v1[4] = {r1.x, r1.y, r1.z, r1.w};
  char* plane = (char*)Bs + g * 1024;
  #pragma unroll
  for (int j = 0; j < 4; ++j) {
    int c = cG * 4 + j;
    unsigned pk = (unsigned)f2bf(v0[j]) | ((unsigned)f2bf(v1[j]) << 16);
    int boff = ((c * 16) ^ (((c >> 3) & 7) << 4)) + slot * 2;
    *(unsigned*)(plane + boff) = pk;
  }
}

__device__ __forceinline__ short8 read_a_frag(const ushort* As, int lg, int row) {
  return *(const short8*)(As + ((lg * 64 + (row ^ lg)) * 8));
}
__device__ __forceinline__ short8 read_b_frag(const ushort* Bs, int lg, int col) {
  int boff = (col * 16) ^ (((col >> 3) & 7) << 4);
  return *(const short8*)((const char*)Bs + lg * 1024 + boff);
}

// ---------------------------------------------------------------------
// Dense GEMM: C(MxN,f32) = A(MxK,f32) @ B(KxN,f32), internally bf16 MFMA
// ---------------------------------------------------------------------
__global__ __launch_bounds__(256) void gemm_bf16_kernel(
    const float* __restrict__ A, const float* __restrict__ B,
    float* __restrict__ C, int M, int N, int K) {
  __shared__ ushort As[2048];
  __shared__ ushort Bs[2048];
  int tid = threadIdx.x;
  int row0 = blockIdx.y * 64, col0 = blockIdx.x * 64;
  int wid = tid >> 6, lane = tid & 63;
  int wm = (wid >> 1) * 32, wn = (wid & 1) * 32;
  int lg = lane >> 4, lr = lane & 15;
  const float* arow = A + (size_t)(row0 + (tid >> 2)) * K;
  f32x4 acc[2][2] = {};
  for (int k0 = 0; k0 < K; k0 += 32) {
    stage_A_tile(arow, k0, As, tid);
    stage_B_tile(B, N, k0, col0, Bs, tid);
    __syncthreads();
    short8 af[2], bfr[2];
    #pragma unroll
    for (int mm = 0; mm < 2; ++mm) af[mm] = read_a_frag(As, lg, wm + mm * 16 + lr);
    #pragma unroll
    for (int nn = 0; nn < 2; ++nn) bfr[nn] = read_b_frag(Bs, lg, wn + nn * 16 + lr);
    #pragma unroll
    for (int mm = 0; mm < 2; ++mm)
      #pragma unroll
      for (int nn = 0; nn < 2; ++nn)
        acc[mm][nn] = __builtin_amdgcn_mfma_f32_16x16x32_bf16(af[mm], bfr[nn], acc[mm][nn], 0, 0, 0);
    __syncthreads();
  }
  #pragma unroll
  for (int mm = 0; mm < 2; ++mm)
    #pragma unroll
    for (int nn = 0; nn < 2; ++nn) {
      int row = row0 + wm + mm * 16 + lg * 4;
      int col = col0 + wn + nn * 16 + lr;
      #pragma unroll
      for (int i = 0; i < 4; ++i)
        C[(size_t)(row + i) * N + col] = acc[mm][nn][i];
    }
}

// ---------------------------------------------------------------------
// MoE up-proj (gathered A, dual-B g/u, fused SiLU*mul epilogue)
// ---------------------------------------------------------------------
__global__ __launch_bounds__(256) void moe_up_mfma_kernel(
    const float* __restrict__ hln, const float* __restrict__ Wgu,
    const int* __restrict__ perm, const int* __restrict__ offs,
    const int* __restrict__ counts, float* __restrict__ act) {
  int e = blockIdx.x;
  int cnt = counts[e];
  int base = blockIdx.y * 64;
  if (base >= cnt) return;
  int start = offs[e];
  int nt = min(64, cnt - base);
  __shared__ int tokmap[64];
  int tid = threadIdx.x;
  if (tid < 64) {
    int idx = start + base + ((tid < nt) ? tid : 0);
    tokmap[tid] = perm[idx] >> 2;
  }
  __shared__ ushort As[2048];
  __shared__ ushort Bg[2048];
  __shared__ ushort Bu[2048];
  __syncthreads();
  int col0 = blockIdx.z * 64;
  const float* W = Wgu + (size_t)e * HH * (2 * IMID);
  const float* arow = hln + (size_t)tokmap[tid >> 2] * HH;
  int wid = tid >> 6, lane = tid & 63;
  int wm = (wid >> 1) * 32, wn = (wid & 1) * 32;
  int lg = lane >> 4, lr = lane & 15;
  f32x4 accg[2][2] = {};
  f32x4 accu[2][2] = {};
  for (int k0 = 0; k0 < HH; k0 += 32) {
    stage_A_tile(arow, k0, As, tid);
    stage_B_tile(W, 2 * IMID, k0, col0, Bg, tid);
    stage_B_tile(W, 2 * IMID, k0, IMID + col0, Bu, tid);
    __syncthreads();
    short8 af[2], bg[2], bu[2];
    #pragma unroll
    for (int mm = 0; mm < 2; ++mm) af[mm] = read_a_frag(As, lg, wm + mm * 16 + lr);
    #pragma unroll
    for (int nn = 0; nn < 2; ++nn) {
      bg[nn] = read_b_frag(Bg, lg, wn + nn * 16 + lr);
      bu[nn] = read_b_frag(Bu, lg, wn + nn * 16 + lr);
    }
    #pragma unroll
    for (int mm = 0; mm < 2; ++mm)
      #pragma unroll
      for (int nn = 0; nn < 2; ++nn) {
        accg[mm][nn] = __builtin_amdgcn_mfma_f32_16x16x32_bf16(af[mm], bg[nn], accg[mm][nn], 0, 0, 0);
        accu[mm][nn] = __builtin_amdgcn_mfma_f32_16x16x32_bf16(af[mm], bu[nn], accu[mm][nn], 0, 0, 0);
      }
    __syncthreads();
  }
  #pragma unroll
  for (int mm = 0; mm < 2; ++mm)
    #pragma unroll
    for (int nn = 0; nn < 2; ++nn) {
      #pragma unroll
      for (int i = 0; i < 4; ++i) {
        int r = wm + mm * 16 + lg * 4 + i;
        if (r < nt) {
          float gv = accg[mm][nn][i], uv = accu[mm][nn][i];
          float av = gv / (1.f + expf(-gv)) * uv;
          act[(size_t)(start + base + r) * IMID + col0 + wn + nn * 16 + lr] = av;
        }
      }
    }
}

// ---------------------------------------------------------------------
// MoE down-proj: PARTIAL[pos][1024] = ACT[pos][384] @ Wd[e]
// ---------------------------------------------------------------------
__global__ __launch_bounds__(256) void moe_down_mfma_kernel(
    const float* __restrict__ act, const float* __restrict__ Wd,
    const int* __restrict__ offs, const int* __restrict__ counts,
    float* __restrict__ partial) {
  int e = blockIdx.x;
  int cnt = counts[e];
  int base = blockIdx.y * 64;
  if (base >= cnt) return;
  int start = offs[e];
  int nt = min(64, cnt - base);
  __shared__ ushort As[2048];
  __shared__ ushort Bs[2048];
  int tid = threadIdx.x;
  int col0 = blockIdx.z * 64;
  const float* W = Wd + (size_t)e * IMID * HH;
  const float* arow = act + (size_t)(start + base + (tid >> 2)) * IMID;
  int wid = tid >> 6, lane = tid & 63;
  int wm = (wid >> 1) * 32, wn = (wid & 1) * 32;
  int lg = lane >> 4, lr = lane & 15;
  f32x4 acc[2][2] = {};
  for (int k0 = 0; k0 < IMID; k0 += 32) {
    stage_A_tile(arow, k0, As, tid);
    stage_B_tile(W, HH, k0, col0, Bs, tid);
    __syncthreads();
    short8 af[2], bfr[2];
    #pragma unroll
    for (int mm = 0; mm < 2; ++mm) af[mm] = read_a_frag(As, lg, wm + mm * 16 + lr);
    #pragma unroll
    for (int nn = 0; nn < 2; ++nn) bfr[nn] = read_b_frag(Bs, lg, wn + nn * 16 + lr);
    #pragma unroll
    for (int mm = 0; mm < 2; ++mm)
      #pragma unroll
      for (int nn = 0; nn < 2; ++nn)
        acc[mm][nn] = __builtin_amdgcn_mfma_f32_16x16x32_bf16(af[mm], bfr[nn], acc[mm][nn], 0, 0, 0);
    __syncthreads();
  }
  #pragma unroll
  for (int mm = 0; mm < 2; ++mm)
    #pragma unroll
    for (int nn = 0; nn < 2; ++nn) {
      #pragma unroll
      for (int i = 0; i < 4; ++i) {
        int r = wm + mm * 16 + lg * 4 + i;
        if (r < nt)
          partial[(size_t)(start + base + r) * HH + col0 + wn + nn * 16 + lr] = acc[mm][nn][i];
      }
    }
}

// =====================================================================
// residual add + RMSNorm
// =====================================================================
__global__ __launch_bounds__(256) void add_rms_kernel(
    const float* __restrict__ a, const float* __restrict__ b,
    const float* __restrict__ w, float* __restrict__ sum_out,
    float* __restrict__ ln_out) {
  int t = blockIdx.x, tid = threadIdx.x;
  float4 x = reinterpret_cast<const float4*>(a + (size_t)t*HH)[tid];
  float4 y = reinterpret_cast<const float4*>(b + (size_t)t*HH)[tid];
  x.x += y.x; x.y += y.y; x.z += y.z; x.w += y.w;
  float ss = x.x*x.x + x.y*x.y + x.z*x.z + x.w*x.w;
  #pragma unroll
  for (int off = 1; off < 64; off <<= 1) ss += __shfl_xor(ss, off);
  __shared__ float wsum[4];
  int wid = tid >> 6, lane = tid & 63;
  if (lane == 0) wsum[wid] = ss;
  __syncthreads();
  float tot = wsum[0] + wsum[1] + wsum[2] + wsum[3];
  float r = rsqrtf(tot * (1.0f/HH) + EPS_);
  reinterpret_cast<float4*>(sum_out + (size_t)t*HH)[tid] = x;
  float4 wl = reinterpret_cast<const float4*>(w)[tid];
  float4 o = make_float4(x.x*r*wl.x, x.y*r*wl.y, x.z*r*wl.z, x.w*r*wl.w);
  reinterpret_cast<float4*>(ln_out + (size_t)t*HH)[tid] = o;
}

// =====================================================================
// per-(t,head) QK RMSNorm + RoPE, in-place
// =====================================================================
__global__ __launch_bounds__(256) void qk_norm_rope_kernel(
    float* __restrict__ qkv, const float* __restrict__ qw,
    const float* __restrict__ kw, const int* __restrict__ pos) {
  int t = blockIdx.x;
  int hh = blockIdx.y * 4 + (threadIdx.x >> 6);
  int lane = threadIdx.x & 63;
  float* p = qkv + (size_t)t * QKV_W + hh * HDIM;
  float x = p[lane];
  float ss = x * x;
  #pragma unroll
  for (int off = 1; off < 64; off <<= 1) ss += __shfl_xor(ss, off);
  float r = rsqrtf(ss * (1.0f/HDIM) + EPS_);
  float wv = (hh < NHEADS ? qw : kw)[lane];
  float xn = x * r * wv;
  float partner = __shfl_xor(xn, 16);
  float out = xn;
  if (lane < 32) {
    int i = lane & 15;
    float inv = powf(10000.0f, -(float)i / 16.0f);
    float ang = (float)pos[t] * inv;
    float cv = cosf(ang), sv = sinf(ang);
    out = (lane < 16) ? (xn * cv - partner * sv) : (partner * sv + xn * cv);
  }
  p[lane] = out;
}

// =====================================================================
// MFMA flash attention. grid (T/64, NH), 4 waves; wave owns 16 q-rows.
// Swapped QK^T: S^T = mfma(K-frag, Q-frag) puts P directly in PV's
// A-fragment layout (A-frag(X) == B-frag(X^T) bitwise).
// =====================================================================
__global__ __launch_bounds__(256) void attn_mfma_kernel(
    const float* __restrict__ qkv, float* __restrict__ o) {
  __shared__ ushort Ks[2048];   // 32 kv-rows x 64 dims, A-tile layout (2 chunks)
  __shared__ ushort Vs[2048];   // 32 kv-rows x 64 dims, B-tile layout
  int tid = threadIdx.x;
  int wid = tid >> 6, lane = tid & 63;
  int lg = lane >> 4, lr = lane & 15;
  int h = blockIdx.y, kvh = h >> 2;
  int q0 = blockIdx.x * 64 + wid * 16;          // wave's q base
  int qg = q0 + lr;                              // this lane's q row (softmax view)

  // Q fragments (B-frag of Q^T): qb[c] = Q[qg][{32c+4lg+j, 32c+16+4lg+j}]
  const float* qrow = qkv + (size_t)qg * QKV_W + h * HDIM;
  short8 qb[2];
  #pragma unroll
  for (int c = 0; c < 2; ++c) {
    float4 a = *(const float4*)(qrow + 32*c + 4*lg);
    float4 b = *(const float4*)(qrow + 32*c + 4*lg + 16);
    short8 v;
    v[0]=(short)f2bf(a.x); v[1]=(short)f2bf(a.y); v[2]=(short)f2bf(a.z); v[3]=(short)f2bf(a.w);
    v[4]=(short)f2bf(b.x); v[5]=(short)f2bf(b.y); v[6]=(short)f2bf(b.z); v[7]=(short)f2bf(b.w);
    qb[c] = v;
  }

  f32x4 o_acc[4] = {};   // O[16q x 64d]: 4 d-chunks, C-layout
  float m_st = -1e30f, l_st = 0.f;
  int kv_end = blockIdx.x * 64 + 64;

  for (int kb = 0; kb * 32 < kv_end; ++kb) {
    // stage K: two 32-dim chunks; c = tid>>7
    {
      int c = tid >> 7, t2 = tid & 127;
      int g = t2 & 3, r = t2 >> 2;
      const float* kp = qkv + (size_t)(kb*32 + r) * QKV_W + NHEADS*HDIM + kvh*HDIM + 32*c + 4*g;
      float4 h0 = *(const float4*)kp;
      float4 h1 = *(const float4*)(kp + 16);
      short8 v;
      v[0]=(short)f2bf(h0.x); v[1]=(short)f2bf(h0.y); v[2]=(short)f2bf(h0.z); v[3]=(short)f2bf(h0.w);
      v[4]=(short)f2bf(h1.x); v[5]=(short)f2bf(h1.y); v[6]=(short)f2bf(h1.z); v[7]=(short)f2bf(h1.w);
      *(short8*)(Ks + c*1024 + (g*32 + (r^g))*8) = v;
    }
    // stage V (B-tile: k=kv rows, col=d) — NOTE: + kvh*HDIM (round-3 fix)
    stage_B_tile(qkv + (size_t)(NHEADS+NKVH)*HDIM + (size_t)kvh*HDIM, QKV_W, kb*32, 0, Vs, tid);
    __syncthreads();

    if (kb * 32 <= q0 + 15) {   // tile not fully masked for this wave
      // S^T fragments: st[n] covers kv rows 16n..16n+15
      f32x4 st[2];
      #pragma unroll
      for (int n = 0; n < 2; ++n) {
        short8 kf0 = *(const short8*)(Ks + 0    + (lg*32 + ((16*n + lr) ^ lg))*8);
        short8 kf1 = *(const short8*)(Ks + 1024 + (lg*32 + ((16*n + lr) ^ lg))*8);
        f32x4 z = {};
        z = __builtin_amdgcn_mfma_f32_16x16x32_bf16(kf0, qb[0], z, 0, 0, 0);
        st[n] = __builtin_amdgcn_mfma_f32_16x16x32_bf16(kf1, qb[1], z, 0, 0, 0);
      }
      // lane l holds S[q=qg][kv = kb*32 + 16n + 4lg + i]
      float s[2][4], tmax = -1e30f;
      #pragma unroll
      for (int n = 0; n < 2; ++n)
        #pragma unroll
        for (int i = 0; i < 4; ++i) {
          int kvg = kb*32 + 16*n + 4*lg + i;
          float sv = st[n][i] * 0.125f;
          if (kvg > qg) sv = -1e30f;
          s[n][i] = sv;
          tmax = fmaxf(tmax, sv);
        }
      tmax = fmaxf(tmax, __shfl_xor(tmax, 16));
      tmax = fmaxf(tmax, __shfl_xor(tmax, 32));
      float m_new = fmaxf(m_st, tmax);
      float corr = __expf(m_st - m_new);
      float p[2][4], psum = 0.f;
      #pragma unroll
      for (int n = 0; n < 2; ++n)
        #pragma unroll
        for (int i = 0; i < 4; ++i) {
          float pv = __expf(s[n][i] - m_new);
          p[n][i] = pv; psum += pv;
        }
      psum += __shfl_xor(psum, 16);
      psum += __shfl_xor(psum, 32);
      l_st = l_st * corr + psum;
      m_st = m_new;
      // rescale O: row r=4lg+i of C-layout needs corr from lane (4lg+i)
      #pragma unroll
      for (int i = 0; i < 4; ++i) {
        float oc = __shfl(corr, 4*lg + i);
        #pragma unroll
        for (int nd = 0; nd < 4; ++nd) o_acc[nd][i] *= oc;
      }
      // P as PV A-fragment: [p[0][0..3], p[1][0..3]]
      short8 pa;
      pa[0]=(short)f2bf(p[0][0]); pa[1]=(short)f2bf(p[0][1]);
      pa[2]=(short)f2bf(p[0][2]); pa[3]=(short)f2bf(p[0][3]);
      pa[4]=(short)f2bf(p[1][0]); pa[5]=(short)f2bf(p[1][1]);
      pa[6]=(short)f2bf(p[1][2]); pa[7]=(short)f2bf(p[1][3]);
      #pragma unroll
      for (int nd = 0; nd < 4; ++nd) {
        short8 vf = read_b_frag(Vs, lg, 16*nd + lr);
        o_acc[nd] = __builtin_amdgcn_mfma_f32_16x16x32_bf16(pa, vf, o_acc[nd], 0, 0, 0);
      }
    }
    __syncthreads();
  }

  // epilogue: divide by l (per row), write out
  #pragma unroll
  for (int i = 0; i < 4; ++i) {
    float lrow = __shfl(l_st, 4*lg + i);
    float inv = 1.0f / lrow;
    int row = q0 + 4*lg + i;
    float* op = o + (size_t)row * (NHEADS*HDIM) + h * HDIM;
    #pragma unroll
    for (int nd = 0; nd < 4; ++nd)
      op[16*nd + lr] = o_acc[nd][i] * inv;
  }
}

// =====================================================================
// router (f32, exact) + grouping
// =====================================================================
__global__ __launch_bounds__(256) void router_kernel(
    const float* __restrict__ hln, const float* __restrict__ Wg,
    const float* __restrict__ bias, int* __restrict__ sel_e,
    float* __restrict__ sel_w, int* __restrict__ counts) {
  int t = blockIdx.x, tid = threadIdx.x;
  __shared__ float hid[HH];
  reinterpret_cast<float4*>(hid)[tid] =
      reinterpret_cast<const float4*>(hln + (size_t)t*HH)[tid];
  __syncthreads();
  int e = tid & 31, ch = tid >> 5;
  float p = 0.f;
  for (int hrow = ch * 128; hrow < ch * 128 + 128; ++hrow)
    p += hid[hrow] * Wg[(size_t)hrow * NEXP + e];
  __shared__ float part[8][32];
  part[ch][e] = p;
  __syncthreads();
  __shared__ float scr_s[32], sfc_s[32];
  if (tid < 32) {
    float lg = 0.f;
    #pragma unroll
    for (int c = 0; c < 8; ++c) lg += part[c][tid];
    float sc = 1.0f / (1.0f + expf(-lg));
    scr_s[tid] = sc;
    sfc_s[tid] = sc + bias[tid];
  }
  __syncthreads();
  if (tid == 0) {
    float gs[NGRP];
    for (int g = 0; g < NGRP; ++g) {
      float m1 = -1e30f, m2 = -1e30f;
      for (int j = 0; j < 8; ++j) {
        float v = sfc_s[g*8 + j];
        if (v > m1) { m2 = m1; m1 = v; } else if (v > m2) m2 = v;
      }
      gs[g] = m1 + m2;
    }
    int g1 = 0;
    for (int g = 1; g < NGRP; ++g) if (gs[g] > gs[g1]) g1 = g;
    int g2 = -1;
    for (int g = 0; g < NGRP; ++g) {
      if (g == g1) continue;
      if (g2 < 0 || gs[g] > gs[g2]) g2 = g;
    }
    bool chosen[NEXP] = {};
    int ids[TOPK_]; float wv[TOPK_]; float wsum = 0.f;
    for (int s = 0; s < TOPK_; ++s) {
      int best = -1; float bv = -1e30f;
      for (int e2 = 0; e2 < NEXP; ++e2) {
        int g = e2 >> 3;
        if (g != g1 && g != g2) continue;
        if (chosen[e2]) continue;
        if (sfc_s[e2] > bv) { bv = sfc_s[e2]; best = e2; }
      }
      chosen[best] = true; ids[s] = best;
      wv[s] = scr_s[best]; wsum += wv[s];
    }
    for (int s = 0; s < TOPK_; ++s) {
      sel_e[t*TOPK_ + s] = ids[s];
      sel_w[t*TOPK_ + s] = wv[s] / wsum;
      atomicAdd(&counts[ids[s]], 1);
    }
  }
}

__global__ void scan_kernel(const int* __restrict__ counts,
                            int* __restrict__ offs, int* __restrict__ cursor) {
  if (threadIdx.x == 0) {
    int acc = 0;
    for (int e = 0; e < NEXP; ++e) { offs[e] = acc; cursor[e] = acc; acc += counts[e]; }
  }
}

__global__ void scatter_kernel(const int* __restrict__ sel_e,
                               int* __restrict__ cursor, int* __restrict__ perm,
                               int* __restrict__ ipos) {
  int i = blockIdx.x * 256 + threadIdx.x;
  if (i < TT * TOPK_) {
    int e = sel_e[i];
    int pos = atomicAdd(&cursor[e], 1);
    perm[pos] = i;
    ipos[i] = pos;
  }
}

// =====================================================================
// shared-expert SiLU*mul
// =====================================================================
__global__ void silu_shared_kernel(const float* __restrict__ gus,
                                   float* __restrict__ shs) {
  int i = blockIdx.x * 256 + threadIdx.x;
  if (i < TT * ISHARED) {
    int t = i / ISHARED, c = i % ISHARED;
    float g = gus[(size_t)t * (2*ISHARED) + c];
    float u = gus[(size_t)t * (2*ISHARED) + c + ISHARED];
    shs[i] = g / (1.f + expf(-g)) * u;
  }
}

// =====================================================================
// final combine
// =====================================================================
__global__ __launch_bounds__(256) void final_combine_kernel(
    const float* __restrict__ partial, const float* __restrict__ sel_w,
    const int* __restrict__ ipos, const float* __restrict__ shared_out,
    float* __restrict__ out_hidden) {
  int t = blockIdx.x, tid = threadIdx.x;
  float w0 = sel_w[t*4], w1 = sel_w[t*4+1], w2 = sel_w[t*4+2], w3 = sel_w[t*4+3];
  int p0 = ipos[t*4], p1 = ipos[t*4+1], p2 = ipos[t*4+2], p3 = ipos[t*4+3];
  float4 a0 = reinterpret_cast<const float4*>(partial + (size_t)p0*HH)[tid];
  float4 a1 = reinterpret_cast<const float4*>(partial + (size_t)p1*HH)[tid];
  float4 a2 = reinterpret_cast<const float4*>(partial + (size_t)p2*HH)[tid];
  float4 a3 = reinterpret_cast<const float4*>(partial + (size_t)p3*HH)[tid];
  float4 sh = reinterpret_cast<const float4*>(shared_out + (size_t)t*HH)[tid];
  float4 r;
  r.x = (w0*a0.x + w1*a1.x + w2*a2.x + w3*a3.x) + sh.x;
  r.y = (w0*a0.y + w1*a1.y + w2*a2.y + w3*a3.y) + sh.y;
  r.z = (w0*a0.z + w1*a1.z + w2*a2.z + w3*a3.z) + sh.z;
  r.w = (w0*a0.w + w1*a1.w + w2*a2.w + w3*a3.w) + sh.w;
  reinterpret_cast<float4*>(out_hidden + (size_t)t*HH)[tid] = r;
}

// =====================================================================
extern "C" void kernel_launch(void* const* d_in, const int* in_sizes, int n_in,
                              void* d_out, int out_size, void* d_ws, size_t ws_size,
                              hipStream_t stream) {
  const float* hidden   = (const float*)d_in[0];
  const float* residual = (const float*)d_in[1];
  const float* in_ln_w  = (const float*)d_in[2];
  const float* post_ln_w= (const float*)d_in[3];
  const float* q_norm_w = (const float*)d_in[4];
  const float* k_norm_w = (const float*)d_in[5];
  const float* Wqkv     = (const float*)d_in[6];
  const float* Wo       = (const float*)d_in[7];
  const float* Wg       = (const float*)d_in[8];
  const float* gate_bias= (const float*)d_in[9];
  const float* Wgu      = (const float*)d_in[10];
  const float* Wd       = (const float*)d_in[11];
  const float* Wgu_sh   = (const float*)d_in[12];
  const float* Wd_sh    = (const float*)d_in[13];
  const int*   positions= (const int*)d_in[14];
  float* out = (float*)d_out;

  float* f = (float*)d_ws;
  size_t off = 0;
  float* R_A   = f + off; off += (size_t)TT*HH;
  float* HLN   = f + off; off += (size_t)TT*HH;
  float* QKV   = f + off; off += (size_t)TT*QKV_W;        // reused as gus
  float* OATT  = f + off; off += (size_t)TT*HH;           // reused as shared_out
  float* HLN2  = f + off; off += (size_t)TT*HH;
  float* SHS   = f + off; off += (size_t)TT*ISHARED;
  float* ACT   = f + off; off += (size_t)(TT*TOPK_ + 64)*IMID;
  float* PARTIAL = f + off; off += (size_t)TT*TOPK_*HH;
  float* SELW  = f + off; off += (size_t)TT*TOPK_;
  int* ibase   = (int*)(f + off);
  int* SELE    = ibase;
  int* PERM    = ibase + TT*TOPK_;
  int* IPOS    = ibase + 2*TT*TOPK_;
  int* COUNTS  = ibase + 3*TT*TOPK_;
  int* OFFS    = COUNTS + NEXP;
  int* CURSOR  = OFFS + NEXP;

  add_rms_kernel<<<TT, 256, 0, stream>>>(hidden, residual, in_ln_w, R_A, HLN);
  gemm_bf16_kernel<<<dim3(QKV_W/64, TT/64), 256, 0, stream>>>(HLN, Wqkv, QKV, TT, QKV_W, HH);
  qk_norm_rope_kernel<<<dim3(TT, 5), 256, 0, stream>>>(QKV, q_norm_w, k_norm_w, positions);
  attn_mfma_kernel<<<dim3(TT/64, NHEADS), 256, 0, stream>>>(QKV, OATT);
  gemm_bf16_kernel<<<dim3(HH/64, TT/64), 256, 0, stream>>>(OATT, Wo, HLN, TT, HH, HH);
  add_rms_kernel<<<TT, 256, 0, stream>>>(HLN, R_A, post_ln_w, out + (size_t)TT*HH, HLN2);
  hipMemsetAsync(COUNTS, 0, NEXP * sizeof(int), stream);
  router_kernel<<<TT, 256, 0, stream>>>(HLN2, Wg, gate_bias, SELE, SELW, COUNTS);
  scan_kernel<<<1, 64, 0, stream>>>(COUNTS, OFFS, CURSOR);
  scatter_kernel<<<(TT*TOPK_ + 255)/256, 256, 0, stream>>>(SELE, CURSOR, PERM, IPOS);
  moe_up_mfma_kernel<<<dim3(NEXP, 32, IMID/64), 256, 0, stream>>>(HLN2, Wgu, PERM, OFFS, COUNTS, ACT);
  moe_down_mfma_kernel<<<dim3(NEXP, 32, HH/64), 256, 0, stream>>>(ACT, Wd, OFFS, COUNTS, PARTIAL);
  gemm_bf16_kernel<<<dim3((2*ISHARED)/64, TT/64), 256, 0, stream>>>(HLN2, Wgu_sh, QKV, TT, 2*ISHARED, HH);
  silu_shared_kernel<<<(TT*ISHARED + 255)/256, 256, 0, stream>>>(QKV, SHS);
  gemm_bf16_kernel<<<dim3(HH/64, TT/64), 256, 0, stream>>>(SHS, Wd_sh, OATT, TT, HH, ISHARED);
  final_combine_kernel<<<TT, 256, 0, stream>>>(PARTIAL, SELW, IPOS, OATT, out);
}

// Round 6
// 452.556 us; speedup vs baseline: 1.1777x; 1.1777x over previous
//
#include <hip/hip_runtime.h>
#include <math.h>

// ---- problem constants ----
#define TT 2048
#define HH 1024
#define NHEADS 16
#define NKVH 4
#define HDIM 64
#define NEXP 32
#define TOPK_ 4
#define NGRP 4
#define IMID 384
#define ISHARED 384
#define QKV_W (24*64)   // 1536
#define EPS_ 1e-5f

typedef __attribute__((ext_vector_type(8))) short short8;
typedef __attribute__((ext_vector_type(4))) float f32x4;

__device__ __forceinline__ ushort f2bf(float x) {
  union { float f; unsigned u; } v; v.f = x;
  unsigned r = v.u + 0x7fffu + ((v.u >> 16) & 1u);
  return (ushort)(r >> 16);
}

// =====================================================================
// MFMA fragment layouts (16x16x32 bf16), verified round 1-5:
//   A-frag lane l: A[row = l&15][k in {4g+j, 16+4g+j}], g = l>>4
//   B-frag lane l: B[k in {4g+j, 16+4g+j}][col = l&15]
//   => A-frag(X) is bitwise identical to B-frag(X^T).
//   C lane l: C[row=(l>>4)*4+i][col = l&15]
// LDS layouts: A-plane [g][row][8] with row^g swizzle; B-plane 16B-granular
// column XOR swizzle. Identical to verified round-5 kernels.
// =====================================================================
__device__ __forceinline__ void write_A_regs(ushort* As, int g, int row,
                                             float4 h0, float4 h1) {
  short8 v;
  v[0]=(short)f2bf(h0.x); v[1]=(short)f2bf(h0.y); v[2]=(short)f2bf(h0.z); v[3]=(short)f2bf(h0.w);
  v[4]=(short)f2bf(h1.x); v[5]=(short)f2bf(h1.y); v[6]=(short)f2bf(h1.z); v[7]=(short)f2bf(h1.w);
  *(short8*)(As + ((g * 128 + (row ^ g)) * 8)) = v;   // 128-row plane
}

__device__ __forceinline__ void write_B_regs(ushort* Bs, int bk, int bc,
                                             float4 r0, float4 r1) {
  int gg = (bk & 15) >> 2;
  int slot = (bk & 3) + ((bk >> 4) << 2);
  char* plane = (char*)Bs + gg * 1024;
  float v0[4] = {r0.x, r0.y, r0.z, r0.w};
  float v1[4] = {r1.x, r1.y, r1.z, r1.w};
  #pragma unroll
  for (int j = 0; j < 4; ++j) {
    int c = bc + j;
    unsigned pk = (unsigned)f2bf(v0[j]) | ((unsigned)f2bf(v1[j]) << 16);
    int boff = ((c * 16) ^ (((c >> 3) & 7) << 4)) + slot * 2;
    *(unsigned*)(plane + boff) = pk;
  }
}

__device__ __forceinline__ short8 read_a_frag128(const ushort* As, int lg, int row) {
  return *(const short8*)(As + ((lg * 128 + (row ^ lg)) * 8));
}
__device__ __forceinline__ short8 read_b_frag(const ushort* Bs, int lg, int col) {
  int boff = (col * 16) ^ (((col >> 3) & 7) << 4);
  return *(const short8*)((const char*)Bs + lg * 1024 + boff);
}

// legacy 64-row B staging (used by attention V)
__device__ __forceinline__ void stage_B_tile(const float* __restrict__ B, int ldb,
                                             int k0, int col0, ushort* Bs, int tid) {
  int a = tid >> 4;
  int cG = tid & 15;
  int k = 2 * a;
  const float* p0 = B + (size_t)(k0 + k) * ldb + col0 + cG * 4;
  const float* p1 = p0 + ldb;
  float4 r0 = *(const float4*)p0;
  float4 r1 = *(const float4*)p1;
  write_B_regs(Bs, k, cG * 4, r0, r1);
}

// ---------------------------------------------------------------------
// Dense GEMM: C(MxN,f32) = A(MxK,f32)@B(KxN,f32). BM=128, BN=64, BK=32.
// 2-phase reg-staged prefetch: loads for k0+32 issue before MFMA of k0.
// ---------------------------------------------------------------------
__global__ __launch_bounds__(256) void gemm128_bf16_kernel(
    const float* __restrict__ A, const float* __restrict__ B,
    float* __restrict__ C, int M, int N, int K) {
  __shared__ ushort As[4096];
  __shared__ ushort Bs[2048];
  int tid = threadIdx.x;
  int row0 = blockIdx.y * 128, col0 = blockIdx.x * 64;
  int g = tid & 3, r = tid >> 2;
  const float* arow0 = A + (size_t)(row0 + r) * K + 4 * g;
  const float* arow1 = arow0 + (size_t)64 * K;
  int bk = (tid >> 4) * 2, bc = (tid & 15) * 4;
  const float* bp = B + (size_t)bk * N + col0 + bc;
  int wid = tid >> 6, lane = tid & 63;
  int lg = lane >> 4, lr = lane & 15;
  int wrow = wid * 32;
  f32x4 acc[2][4] = {};
  float4 a00 = *(const float4*)(arow0);
  float4 a01 = *(const float4*)(arow0 + 16);
  float4 a10 = *(const float4*)(arow1);
  float4 a11 = *(const float4*)(arow1 + 16);
  float4 b0  = *(const float4*)(bp);
  float4 b1  = *(const float4*)(bp + N);
  for (int k0 = 0; k0 < K; k0 += 32) {
    write_A_regs(As, g, r, a00, a01);
    write_A_regs(As, g, r + 64, a10, a11);
    write_B_regs(Bs, bk, bc, b0, b1);
    __syncthreads();
    if (k0 + 32 < K) {
      a00 = *(const float4*)(arow0 + k0 + 32);
      a01 = *(const float4*)(arow0 + k0 + 48);
      a10 = *(const float4*)(arow1 + k0 + 32);
      a11 = *(const float4*)(arow1 + k0 + 48);
      const float* bpn = bp + (size_t)(k0 + 32) * N;
      b0 = *(const float4*)bpn;
      b1 = *(const float4*)(bpn + N);
    }
    short8 af0 = read_a_frag128(As, lg, wrow + lr);
    short8 af1 = read_a_frag128(As, lg, wrow + 16 + lr);
    #pragma unroll
    for (int nn = 0; nn < 4; ++nn) {
      short8 bf_ = read_b_frag(Bs, lg, nn * 16 + lr);
      acc[0][nn] = __builtin_amdgcn_mfma_f32_16x16x32_bf16(af0, bf_, acc[0][nn], 0, 0, 0);
      acc[1][nn] = __builtin_amdgcn_mfma_f32_16x16x32_bf16(af1, bf_, acc[1][nn], 0, 0, 0);
    }
    __syncthreads();
  }
  #pragma unroll
  for (int mm = 0; mm < 2; ++mm)
    #pragma unroll
    for (int nn = 0; nn < 4; ++nn) {
      int row = row0 + wrow + mm * 16 + lg * 4;
      int col = col0 + nn * 16 + lr;
      #pragma unroll
      for (int i = 0; i < 4; ++i)
        C[(size_t)(row + i) * N + col] = acc[mm][nn][i];
    }
}

// ---------------------------------------------------------------------
// MoE up-proj: 128 slots x 64 cols, dual g/u planes, fused SiLU*mul.
// grid (NEXP, 16, IMID/64)
// ---------------------------------------------------------------------
__global__ __launch_bounds__(256) void moe_up_mfma_kernel(
    const float* __restrict__ hln, const float* __restrict__ Wgu,
    const int* __restrict__ perm, const int* __restrict__ offs,
    const int* __restrict__ counts, float* __restrict__ act) {
  int e = blockIdx.x;
  int cnt = counts[e];
  int base = blockIdx.y * 128;
  if (base >= cnt) return;
  int start = offs[e];
  int nt = min(128, cnt - base);
  __shared__ int tokmap[128];
  int tid = threadIdx.x;
  if (tid < 128) {
    int idx = start + base + ((tid < nt) ? tid : 0);
    tokmap[tid] = perm[idx] >> 2;
  }
  __shared__ ushort As[4096];
  __shared__ ushort Bg[2048];
  __shared__ ushort Bu[2048];
  __syncthreads();
  int col0 = blockIdx.z * 64;
  const float* W = Wgu + (size_t)e * HH * (2 * IMID);
  int g = tid & 3, r = tid >> 2;
  const float* arow0 = hln + (size_t)tokmap[r] * HH + 4 * g;
  const float* arow1 = hln + (size_t)tokmap[r + 64] * HH + 4 * g;
  int bk = (tid >> 4) * 2, bc = (tid & 15) * 4;
  const float* bpg = W + (size_t)bk * (2 * IMID) + col0 + bc;
  const float* bpu = bpg + IMID;
  int wid = tid >> 6, lane = tid & 63;
  int lg = lane >> 4, lr = lane & 15;
  int wrow = wid * 32;
  f32x4 accg[2][4] = {}, accu[2][4] = {};
  float4 a00 = *(const float4*)(arow0);
  float4 a01 = *(const float4*)(arow0 + 16);
  float4 a10 = *(const float4*)(arow1);
  float4 a11 = *(const float4*)(arow1 + 16);
  float4 g0  = *(const float4*)(bpg);
  float4 g1  = *(const float4*)(bpg + 2 * IMID);
  float4 u0  = *(const float4*)(bpu);
  float4 u1  = *(const float4*)(bpu + 2 * IMID);
  for (int k0 = 0; k0 < HH; k0 += 32) {
    write_A_regs(As, g, r, a00, a01);
    write_A_regs(As, g, r + 64, a10, a11);
    write_B_regs(Bg, bk, bc, g0, g1);
    write_B_regs(Bu, bk, bc, u0, u1);
    __syncthreads();
    if (k0 + 32 < HH) {
      a00 = *(const float4*)(arow0 + k0 + 32);
      a01 = *(const float4*)(arow0 + k0 + 48);
      a10 = *(const float4*)(arow1 + k0 + 32);
      a11 = *(const float4*)(arow1 + k0 + 48);
      const float* gn = bpg + (size_t)(k0 + 32) * (2 * IMID);
      const float* un = bpu + (size_t)(k0 + 32) * (2 * IMID);
      g0 = *(const float4*)gn;  g1 = *(const float4*)(gn + 2 * IMID);
      u0 = *(const float4*)un;  u1 = *(const float4*)(un + 2 * IMID);
    }
    short8 af0 = read_a_frag128(As, lg, wrow + lr);
    short8 af1 = read_a_frag128(As, lg, wrow + 16 + lr);
    #pragma unroll
    for (int nn = 0; nn < 4; ++nn) {
      short8 bgf = read_b_frag(Bg, lg, nn * 16 + lr);
      short8 buf_ = read_b_frag(Bu, lg, nn * 16 + lr);
      accg[0][nn] = __builtin_amdgcn_mfma_f32_16x16x32_bf16(af0, bgf, accg[0][nn], 0, 0, 0);
      accg[1][nn] = __builtin_amdgcn_mfma_f32_16x16x32_bf16(af1, bgf, accg[1][nn], 0, 0, 0);
      accu[0][nn] = __builtin_amdgcn_mfma_f32_16x16x32_bf16(af0, buf_, accu[0][nn], 0, 0, 0);
      accu[1][nn] = __builtin_amdgcn_mfma_f32_16x16x32_bf16(af1, buf_, accu[1][nn], 0, 0, 0);
    }
    __syncthreads();
  }
  #pragma unroll
  for (int mm = 0; mm < 2; ++mm)
    #pragma unroll
    for (int nn = 0; nn < 4; ++nn)
      #pragma unroll
      for (int i = 0; i < 4; ++i) {
        int rr = wrow + mm * 16 + lg * 4 + i;
        if (rr < nt) {
          float gv = accg[mm][nn][i], uv = accu[mm][nn][i];
          float av = gv / (1.f + expf(-gv)) * uv;
          act[(size_t)(start + base + rr) * IMID + col0 + nn * 16 + lr] = av;
        }
      }
}

// ---------------------------------------------------------------------
// MoE down-proj: 128 slots x 64 cols, K=IMID. grid (NEXP, 16, HH/64)
// ---------------------------------------------------------------------
__global__ __launch_bounds__(256) void moe_down_mfma_kernel(
    const float* __restrict__ act, const float* __restrict__ Wd,
    const int* __restrict__ offs, const int* __restrict__ counts,
    float* __restrict__ partial) {
  int e = blockIdx.x;
  int cnt = counts[e];
  int base = blockIdx.y * 128;
  if (base >= cnt) return;
  int start = offs[e];
  int nt = min(128, cnt - base);
  __shared__ ushort As[4096];
  __shared__ ushort Bs[2048];
  int tid = threadIdx.x;
  int col0 = blockIdx.z * 64;
  const float* W = Wd + (size_t)e * IMID * HH;
  int g = tid & 3, r = tid >> 2;
  const float* arow0 = act + (size_t)(start + base + r) * IMID + 4 * g;
  const float* arow1 = arow0 + (size_t)64 * IMID;
  int bk = (tid >> 4) * 2, bc = (tid & 15) * 4;
  const float* bp = W + (size_t)bk * HH + col0 + bc;
  int wid = tid >> 6, lane = tid & 63;
  int lg = lane >> 4, lr = lane & 15;
  int wrow = wid * 32;
  f32x4 acc[2][4] = {};
  float4 a00 = *(const float4*)(arow0);
  float4 a01 = *(const float4*)(arow0 + 16);
  float4 a10 = *(const float4*)(arow1);
  float4 a11 = *(const float4*)(arow1 + 16);
  float4 b0  = *(const float4*)(bp);
  float4 b1  = *(const float4*)(bp + HH);
  for (int k0 = 0; k0 < IMID; k0 += 32) {
    write_A_regs(As, g, r, a00, a01);
    write_A_regs(As, g, r + 64, a10, a11);
    write_B_regs(Bs, bk, bc, b0, b1);
    __syncthreads();
    if (k0 + 32 < IMID) {
      a00 = *(const float4*)(arow0 + k0 + 32);
      a01 = *(const float4*)(arow0 + k0 + 48);
      a10 = *(const float4*)(arow1 + k0 + 32);
      a11 = *(const float4*)(arow1 + k0 + 48);
      const float* bpn = bp + (size_t)(k0 + 32) * HH;
      b0 = *(const float4*)bpn;
      b1 = *(const float4*)(bpn + HH);
    }
    short8 af0 = read_a_frag128(As, lg, wrow + lr);
    short8 af1 = read_a_frag128(As, lg, wrow + 16 + lr);
    #pragma unroll
    for (int nn = 0; nn < 4; ++nn) {
      short8 bf_ = read_b_frag(Bs, lg, nn * 16 + lr);
      acc[0][nn] = __builtin_amdgcn_mfma_f32_16x16x32_bf16(af0, bf_, acc[0][nn], 0, 0, 0);
      acc[1][nn] = __builtin_amdgcn_mfma_f32_16x16x32_bf16(af1, bf_, acc[1][nn], 0, 0, 0);
    }
    __syncthreads();
  }
  #pragma unroll
  for (int mm = 0; mm < 2; ++mm)
    #pragma unroll
    for (int nn = 0; nn < 4; ++nn)
      #pragma unroll
      for (int i = 0; i < 4; ++i) {
        int rr = wrow + mm * 16 + lg * 4 + i;
        if (rr < nt)
          partial[(size_t)(start + base + rr) * HH + col0 + nn * 16 + lr] = acc[mm][nn][i];
      }
}

// =====================================================================
// residual add + RMSNorm
// =====================================================================
__global__ __launch_bounds__(256) void add_rms_kernel(
    const float* __restrict__ a, const float* __restrict__ b,
    const float* __restrict__ w, float* __restrict__ sum_out,
    float* __restrict__ ln_out) {
  int t = blockIdx.x, tid = threadIdx.x;
  float4 x = reinterpret_cast<const float4*>(a + (size_t)t*HH)[tid];
  float4 y = reinterpret_cast<const float4*>(b + (size_t)t*HH)[tid];
  x.x += y.x; x.y += y.y; x.z += y.z; x.w += y.w;
  float ss = x.x*x.x + x.y*x.y + x.z*x.z + x.w*x.w;
  #pragma unroll
  for (int off = 1; off < 64; off <<= 1) ss += __shfl_xor(ss, off);
  __shared__ float wsum[4];
  int wid = tid >> 6, lane = tid & 63;
  if (lane == 0) wsum[wid] = ss;
  __syncthreads();
  float tot = wsum[0] + wsum[1] + wsum[2] + wsum[3];
  float r = rsqrtf(tot * (1.0f/HH) + EPS_);
  reinterpret_cast<float4*>(sum_out + (size_t)t*HH)[tid] = x;
  float4 wl = reinterpret_cast<const float4*>(w)[tid];
  float4 o = make_float4(x.x*r*wl.x, x.y*r*wl.y, x.z*r*wl.z, x.w*r*wl.w);
  reinterpret_cast<float4*>(ln_out + (size_t)t*HH)[tid] = o;
}

// =====================================================================
// per-(t,head) QK RMSNorm + RoPE, in-place
// =====================================================================
__global__ __launch_bounds__(256) void qk_norm_rope_kernel(
    float* __restrict__ qkv, const float* __restrict__ qw,
    const float* __restrict__ kw, const int* __restrict__ pos) {
  int t = blockIdx.x;
  int hh = blockIdx.y * 4 + (threadIdx.x >> 6);
  int lane = threadIdx.x & 63;
  float* p = qkv + (size_t)t * QKV_W + hh * HDIM;
  float x = p[lane];
  float ss = x * x;
  #pragma unroll
  for (int off = 1; off < 64; off <<= 1) ss += __shfl_xor(ss, off);
  float r = rsqrtf(ss * (1.0f/HDIM) + EPS_);
  float wv = (hh < NHEADS ? qw : kw)[lane];
  float xn = x * r * wv;
  float partner = __shfl_xor(xn, 16);
  float out = xn;
  if (lane < 32) {
    int i = lane & 15;
    float inv = powf(10000.0f, -(float)i / 16.0f);
    float ang = (float)pos[t] * inv;
    float cv = cosf(ang), sv = sinf(ang);
    out = (lane < 16) ? (xn * cv - partner * sv) : (partner * sv + xn * cv);
  }
  p[lane] = out;
}

// =====================================================================
// MFMA flash attention (verified round 5). grid (T/64, NH), 4 waves.
// =====================================================================
__global__ __launch_bounds__(256) void attn_mfma_kernel(
    const float* __restrict__ qkv, float* __restrict__ o) {
  __shared__ ushort Ks[2048];
  __shared__ ushort Vs[2048];
  int tid = threadIdx.x;
  int wid = tid >> 6, lane = tid & 63;
  int lg = lane >> 4, lr = lane & 15;
  int h = blockIdx.y, kvh = h >> 2;
  int q0 = blockIdx.x * 64 + wid * 16;
  int qg = q0 + lr;

  const float* qrow = qkv + (size_t)qg * QKV_W + h * HDIM;
  short8 qb[2];
  #pragma unroll
  for (int c = 0; c < 2; ++c) {
    float4 a = *(const float4*)(qrow + 32*c + 4*lg);
    float4 b = *(const float4*)(qrow + 32*c + 4*lg + 16);
    short8 v;
    v[0]=(short)f2bf(a.x); v[1]=(short)f2bf(a.y); v[2]=(short)f2bf(a.z); v[3]=(short)f2bf(a.w);
    v[4]=(short)f2bf(b.x); v[5]=(short)f2bf(b.y); v[6]=(short)f2bf(b.z); v[7]=(short)f2bf(b.w);
    qb[c] = v;
  }

  f32x4 o_acc[4] = {};
  float m_st = -1e30f, l_st = 0.f;
  int kv_end = blockIdx.x * 64 + 64;

  for (int kb = 0; kb * 32 < kv_end; ++kb) {
    {
      int c = tid >> 7, t2 = tid & 127;
      int g = t2 & 3, r = t2 >> 2;
      const float* kp = qkv + (size_t)(kb*32 + r) * QKV_W + NHEADS*HDIM + kvh*HDIM + 32*c + 4*g;
      float4 h0 = *(const float4*)kp;
      float4 h1 = *(const float4*)(kp + 16);
      short8 v;
      v[0]=(short)f2bf(h0.x); v[1]=(short)f2bf(h0.y); v[2]=(short)f2bf(h0.z); v[3]=(short)f2bf(h0.w);
      v[4]=(short)f2bf(h1.x); v[5]=(short)f2bf(h1.y); v[6]=(short)f2bf(h1.z); v[7]=(short)f2bf(h1.w);
      *(short8*)(Ks + c*1024 + (g*32 + (r^g))*8) = v;
    }
    stage_B_tile(qkv + (size_t)(NHEADS+NKVH)*HDIM + (size_t)kvh*HDIM, QKV_W, kb*32, 0, Vs, tid);
    __syncthreads();

    if (kb * 32 <= q0 + 15) {
      f32x4 st[2];
      #pragma unroll
      for (int n = 0; n < 2; ++n) {
        short8 kf0 = *(const short8*)(Ks + 0    + (lg*32 + ((16*n + lr) ^ lg))*8);
        short8 kf1 = *(const short8*)(Ks + 1024 + (lg*32 + ((16*n + lr) ^ lg))*8);
        f32x4 z = {};
        z = __builtin_amdgcn_mfma_f32_16x16x32_bf16(kf0, qb[0], z, 0, 0, 0);
        st[n] = __builtin_amdgcn_mfma_f32_16x16x32_bf16(kf1, qb[1], z, 0, 0, 0);
      }
      float s[2][4], tmax = -1e30f;
      #pragma unroll
      for (int n = 0; n < 2; ++n)
        #pragma unroll
        for (int i = 0; i < 4; ++i) {
          int kvg = kb*32 + 16*n + 4*lg + i;
          float sv = st[n][i] * 0.125f;
          if (kvg > qg) sv = -1e30f;
          s[n][i] = sv;
          tmax = fmaxf(tmax, sv);
        }
      tmax = fmaxf(tmax, __shfl_xor(tmax, 16));
      tmax = fmaxf(tmax, __shfl_xor(tmax, 32));
      float m_new = fmaxf(m_st, tmax);
      float corr = __expf(m_st - m_new);
      float p[2][4], psum = 0.f;
      #pragma unroll
      for (int n = 0; n < 2; ++n)
        #pragma unroll
        for (int i = 0; i < 4; ++i) {
          float pv = __expf(s[n][i] - m_new);
          p[n][i] = pv; psum += pv;
        }
      psum += __shfl_xor(psum, 16);
      psum += __shfl_xor(psum, 32);
      l_st = l_st * corr + psum;
      m_st = m_new;
      #pragma unroll
      for (int i = 0; i < 4; ++i) {
        float oc = __shfl(corr, 4*lg + i);
        #pragma unroll
        for (int nd = 0; nd < 4; ++nd) o_acc[nd][i] *= oc;
      }
      short8 pa;
      pa[0]=(short)f2bf(p[0][0]); pa[1]=(short)f2bf(p[0][1]);
      pa[2]=(short)f2bf(p[0][2]); pa[3]=(short)f2bf(p[0][3]);
      pa[4]=(short)f2bf(p[1][0]); pa[5]=(short)f2bf(p[1][1]);
      pa[6]=(short)f2bf(p[1][2]); pa[7]=(short)f2bf(p[1][3]);
      #pragma unroll
      for (int nd = 0; nd < 4; ++nd) {
        short8 vf = read_b_frag(Vs, lg, 16*nd + lr);
        o_acc[nd] = __builtin_amdgcn_mfma_f32_16x16x32_bf16(pa, vf, o_acc[nd], 0, 0, 0);
      }
    }
    __syncthreads();
  }

  #pragma unroll
  for (int i = 0; i < 4; ++i) {
    float lrow = __shfl(l_st, 4*lg + i);
    float inv = 1.0f / lrow;
    int row = q0 + 4*lg + i;
    float* op = o + (size_t)row * (NHEADS*HDIM) + h * HDIM;
    #pragma unroll
    for (int nd = 0; nd < 4; ++nd)
      op[16*nd + lr] = o_acc[nd][i] * inv;
  }
}

// =====================================================================
// router (f32, exact) + grouping
// =====================================================================
__global__ __launch_bounds__(256) void router_kernel(
    const float* __restrict__ hln, const float* __restrict__ Wg,
    const float* __restrict__ bias, int* __restrict__ sel_e,
    float* __restrict__ sel_w, int* __restrict__ counts) {
  int t = blockIdx.x, tid = threadIdx.x;
  __shared__ float hid[HH];
  reinterpret_cast<float4*>(hid)[tid] =
      reinterpret_cast<const float4*>(hln + (size_t)t*HH)[tid];
  __syncthreads();
  int e = tid & 31, ch = tid >> 5;
  float p = 0.f;
  for (int hrow = ch * 128; hrow < ch * 128 + 128; ++hrow)
    p += hid[hrow] * Wg[(size_t)hrow * NEXP + e];
  __shared__ float part[8][32];
  part[ch][e] = p;
  __syncthreads();
  __shared__ float scr_s[32], sfc_s[32];
  if (tid < 32) {
    float lg = 0.f;
    #pragma unroll
    for (int c = 0; c < 8; ++c) lg += part[c][tid];
    float sc = 1.0f / (1.0f + expf(-lg));
    scr_s[tid] = sc;
    sfc_s[tid] = sc + bias[tid];
  }
  __syncthreads();
  if (tid == 0) {
    float gs[NGRP];
    for (int g = 0; g < NGRP; ++g) {
      float m1 = -1e30f, m2 = -1e30f;
      for (int j = 0; j < 8; ++j) {
        float v = sfc_s[g*8 + j];
        if (v > m1) { m2 = m1; m1 = v; } else if (v > m2) m2 = v;
      }
      gs[g] = m1 + m2;
    }
    int g1 = 0;
    for (int g = 1; g < NGRP; ++g) if (gs[g] > gs[g1]) g1 = g;
    int g2 = -1;
    for (int g = 0; g < NGRP; ++g) {
      if (g == g1) continue;
      if (g2 < 0 || gs[g] > gs[g2]) g2 = g;
    }
    bool chosen[NEXP] = {};
    int ids[TOPK_]; float wv[TOPK_]; float wsum = 0.f;
    for (int s = 0; s < TOPK_; ++s) {
      int best = -1; float bv = -1e30f;
      for (int e2 = 0; e2 < NEXP; ++e2) {
        int g = e2 >> 3;
        if (g != g1 && g != g2) continue;
        if (chosen[e2]) continue;
        if (sfc_s[e2] > bv) { bv = sfc_s[e2]; best = e2; }
      }
      chosen[best] = true; ids[s] = best;
      wv[s] = scr_s[best]; wsum += wv[s];
    }
    for (int s = 0; s < TOPK_; ++s) {
      sel_e[t*TOPK_ + s] = ids[s];
      sel_w[t*TOPK_ + s] = wv[s] / wsum;
      atomicAdd(&counts[ids[s]], 1);
    }
  }
}

__global__ void scan_kernel(const int* __restrict__ counts,
                            int* __restrict__ offs, int* __restrict__ cursor) {
  if (threadIdx.x == 0) {
    int acc = 0;
    for (int e = 0; e < NEXP; ++e) { offs[e] = acc; cursor[e] = acc; acc += counts[e]; }
  }
}

__global__ void scatter_kernel(const int* __restrict__ sel_e,
                               int* __restrict__ cursor, int* __restrict__ perm,
                               int* __restrict__ ipos) {
  int i = blockIdx.x * 256 + threadIdx.x;
  if (i < TT * TOPK_) {
    int e = sel_e[i];
    int pos = atomicAdd(&cursor[e], 1);
    perm[pos] = i;
    ipos[i] = pos;
  }
}

// =====================================================================
// shared-expert SiLU*mul
// =====================================================================
__global__ void silu_shared_kernel(const float* __restrict__ gus,
                                   float* __restrict__ shs) {
  int i = blockIdx.x * 256 + threadIdx.x;
  if (i < TT * ISHARED) {
    int t = i / ISHARED, c = i % ISHARED;
    float g = gus[(size_t)t * (2*ISHARED) + c];
    float u = gus[(size_t)t * (2*ISHARED) + c + ISHARED];
    shs[i] = g / (1.f + expf(-g)) * u;
  }
}

// =====================================================================
// final combine
// =====================================================================
__global__ __launch_bounds__(256) void final_combine_kernel(
    const float* __restrict__ partial, const float* __restrict__ sel_w,
    const int* __restrict__ ipos, const float* __restrict__ shared_out,
    float* __restrict__ out_hidden) {
  int t = blockIdx.x, tid = threadIdx.x;
  float w0 = sel_w[t*4], w1 = sel_w[t*4+1], w2 = sel_w[t*4+2], w3 = sel_w[t*4+3];
  int p0 = ipos[t*4], p1 = ipos[t*4+1], p2 = ipos[t*4+2], p3 = ipos[t*4+3];
  float4 a0 = reinterpret_cast<const float4*>(partial + (size_t)p0*HH)[tid];
  float4 a1 = reinterpret_cast<const float4*>(partial + (size_t)p1*HH)[tid];
  float4 a2 = reinterpret_cast<const float4*>(partial + (size_t)p2*HH)[tid];
  float4 a3 = reinterpret_cast<const float4*>(partial + (size_t)p3*HH)[tid];
  float4 sh = reinterpret_cast<const float4*>(shared_out + (size_t)t*HH)[tid];
  float4 r;
  r.x = (w0*a0.x + w1*a1.x + w2*a2.x + w3*a3.x) + sh.x;
  r.y = (w0*a0.y + w1*a1.y + w2*a2.y + w3*a3.y) + sh.y;
  r.z = (w0*a0.z + w1*a1.z + w2*a2.z + w3*a3.z) + sh.z;
  r.w = (w0*a0.w + w1*a1.w + w2*a2.w + w3*a3.w) + sh.w;
  reinterpret_cast<float4*>(out_hidden + (size_t)t*HH)[tid] = r;
}

// =====================================================================
extern "C" void kernel_launch(void* const* d_in, const int* in_sizes, int n_in,
                              void* d_out, int out_size, void* d_ws, size_t ws_size,
                              hipStream_t stream) {
  const float* hidden   = (const float*)d_in[0];
  const float* residual = (const float*)d_in[1];
  const float* in_ln_w  = (const float*)d_in[2];
  const float* post_ln_w= (const float*)d_in[3];
  const float* q_norm_w = (const float*)d_in[4];
  const float* k_norm_w = (const float*)d_in[5];
  const float* Wqkv     = (const float*)d_in[6];
  const float* Wo       = (const float*)d_in[7];
  const float* Wg       = (const float*)d_in[8];
  const float* gate_bias= (const float*)d_in[9];
  const float* Wgu      = (const float*)d_in[10];
  const float* Wd       = (const float*)d_in[11];
  const float* Wgu_sh   = (const float*)d_in[12];
  const float* Wd_sh    = (const float*)d_in[13];
  const int*   positions= (const int*)d_in[14];
  float* out = (float*)d_out;

  float* f = (float*)d_ws;
  size_t off = 0;
  float* R_A   = f + off; off += (size_t)TT*HH;
  float* HLN   = f + off; off += (size_t)TT*HH;
  float* QKV   = f + off; off += (size_t)TT*QKV_W;        // reused as gus
  float* OATT  = f + off; off += (size_t)TT*HH;           // reused as shared_out
  float* HLN2  = f + off; off += (size_t)TT*HH;
  float* SHS   = f + off; off += (size_t)TT*ISHARED;
  float* ACT   = f + off; off += (size_t)(TT*TOPK_ + 128)*IMID;  // +128 pad rows
  float* PARTIAL = f + off; off += (size_t)TT*TOPK_*HH;
  float* SELW  = f + off; off += (size_t)TT*TOPK_;
  int* ibase   = (int*)(f + off);
  int* SELE    = ibase;
  int* PERM    = ibase + TT*TOPK_;
  int* IPOS    = ibase + 2*TT*TOPK_;
  int* COUNTS  = ibase + 3*TT*TOPK_;
  int* OFFS    = COUNTS + NEXP;
  int* CURSOR  = OFFS + NEXP;

  add_rms_kernel<<<TT, 256, 0, stream>>>(hidden, residual, in_ln_w, R_A, HLN);
  gemm128_bf16_kernel<<<dim3(QKV_W/64, TT/128), 256, 0, stream>>>(HLN, Wqkv, QKV, TT, QKV_W, HH);
  qk_norm_rope_kernel<<<dim3(TT, 5), 256, 0, stream>>>(QKV, q_norm_w, k_norm_w, positions);
  attn_mfma_kernel<<<dim3(TT/64, NHEADS), 256, 0, stream>>>(QKV, OATT);
  gemm128_bf16_kernel<<<dim3(HH/64, TT/128), 256, 0, stream>>>(OATT, Wo, HLN, TT, HH, HH);
  add_rms_kernel<<<TT, 256, 0, stream>>>(HLN, R_A, post_ln_w, out + (size_t)TT*HH, HLN2);
  hipMemsetAsync(COUNTS, 0, NEXP * sizeof(int), stream);
  router_kernel<<<TT, 256, 0, stream>>>(HLN2, Wg, gate_bias, SELE, SELW, COUNTS);
  scan_kernel<<<1, 64, 0, stream>>>(COUNTS, OFFS, CURSOR);
  scatter_kernel<<<(TT*TOPK_ + 255)/256, 256, 0, stream>>>(SELE, CURSOR, PERM, IPOS);
  moe_up_mfma_kernel<<<dim3(NEXP, 16, IMID/64), 256, 0, stream>>>(HLN2, Wgu, PERM, OFFS, COUNTS, ACT);
  moe_down_mfma_kernel<<<dim3(NEXP, 16, HH/64), 256, 0, stream>>>(ACT, Wd, OFFS, COUNTS, PARTIAL);
  gemm128_bf16_kernel<<<dim3((2*ISHARED)/64, TT/128), 256, 0, stream>>>(HLN2, Wgu_sh, QKV, TT, 2*ISHARED, HH);
  silu_shared_kernel<<<(TT*ISHARED + 255)/256, 256, 0, stream>>>(QKV, SHS);
  gemm128_bf16_kernel<<<dim3(HH/64, TT/128), 256, 0, stream>>>(SHS, Wd_sh, OATT, TT, HH, ISHARED);
  final_combine_kernel<<<TT, 256, 0, stream>>>(PARTIAL, SELW, IPOS, OATT, out);
}